// Round 1
// baseline (7613.998 us; speedup 1.0000x reference)
//
#include <hip/hip_runtime.h>
#include <hip/hip_bf16.h>

#define NNODE 50000
#define EDIM  256
#define HDIM  512
#define NEXP  5
#define GHID  128
#define NEDGE 800000

typedef __attribute__((ext_vector_type(8))) short  short8;
typedef __attribute__((ext_vector_type(4))) float  float4v;

__device__ __forceinline__ float fast_tanh(float y) {
    float ay = fabsf(y);
    float e  = __expf(-2.0f * ay);
    float t  = (1.0f - e) / (1.0f + e);
    return (y < 0.0f) ? -t : t;
}
__device__ __forceinline__ float gelu_tanh(float x) {
    float inner = 0.7978845608028654f * (x + 0.044715f * x * x * x);
    return 0.5f * x * (1.0f + fast_tanh(inner));
}

// ---------- weight transpose + fp32->bf16 (out[b][c][r] = bf16(in[b][r][c])) ----------
__global__ void wtrans(const float* __restrict__ in, unsigned short* __restrict__ out,
                       int B, int R, int C) {
    int total = B * R * C;
    for (int i = blockIdx.x * blockDim.x + threadIdx.x; i < total; i += gridDim.x * blockDim.x) {
        int rc  = R * C;
        int b   = i / rc;
        int rem = i - b * rc;
        int c   = rem / R;
        int r   = rem - c * R;
        float f = in[(size_t)b * rc + (size_t)r * C + c];
        unsigned u = __builtin_bit_cast(unsigned, f);
        u += 0x7FFFu + ((u >> 16) & 1u);
        out[i] = (unsigned short)(u >> 16);
    }
}

// ---------- gate GEMM: g = relu(concat(text,tab,str) @ Wg1 + bg1), fp32 ----------
// block: 256 thr; 16 rows x 128 cols per block. thread: 2 rows x 4 cols.
__global__ __launch_bounds__(256) void gate_gemm(
    const float* __restrict__ text, const float* __restrict__ tab, const float* __restrict__ str,
    const float* __restrict__ Wg1, const float* __restrict__ bg1, float* __restrict__ g) {
    int jg = threadIdx.x & 31;   // col group: cols 4*jg..4*jg+3
    int rp = threadIdx.x >> 5;   // 0..7 -> rows rp*2, rp*2+1
    int r0 = blockIdx.x * 16 + rp * 2;
    float acc[2][4] = {{0.f,0.f,0.f,0.f},{0.f,0.f,0.f,0.f}};
    const float* xsrc[3] = { text, tab, str };
    for (int part = 0; part < 3; ++part) {
        const float* x0 = xsrc[part] + (size_t)r0 * EDIM;
        const float* wp = Wg1 + (size_t)part * EDIM * GHID + 4 * jg;
        for (int k = 0; k < EDIM; k += 4) {
            float4v xa = *(const float4v*)(x0 + k);
            float4v xb = *(const float4v*)(x0 + EDIM + k);
            float4v w0 = *(const float4v*)(wp + (size_t)(k + 0) * GHID);
            float4v w1 = *(const float4v*)(wp + (size_t)(k + 1) * GHID);
            float4v w2 = *(const float4v*)(wp + (size_t)(k + 2) * GHID);
            float4v w3 = *(const float4v*)(wp + (size_t)(k + 3) * GHID);
#pragma unroll
            for (int c = 0; c < 4; ++c) {
                acc[0][c] += xa[0]*w0[c] + xa[1]*w1[c] + xa[2]*w2[c] + xa[3]*w3[c];
                acc[1][c] += xb[0]*w0[c] + xb[1]*w1[c] + xb[2]*w2[c] + xb[3]*w3[c];
            }
        }
    }
    int j = 4 * jg;
#pragma unroll
    for (int rr = 0; rr < 2; ++rr) {
        float4v o;
#pragma unroll
        for (int c = 0; c < 4; ++c) o[c] = fmaxf(acc[rr][c] + bg1[j + c], 0.0f);
        *(float4v*)(g + (size_t)(r0 + rr) * GHID + j) = o;
    }
}

// ---------- gating: logits -> softmax -> top2 -> normalized gates (fp32) ----------
__global__ __launch_bounds__(256) void gating(
    const float* __restrict__ g, const float* __restrict__ Wg2, const float* __restrict__ bg2,
    float* __restrict__ gates, int* __restrict__ esel) {
    int wv = threadIdx.x >> 6, lane = threadIdx.x & 63;
    int n = blockIdx.x * 4 + wv;
    float p[NEXP];
    float g1 = g[(size_t)n * GHID + lane];
    float g2 = g[(size_t)n * GHID + 64 + lane];
#pragma unroll
    for (int e = 0; e < NEXP; ++e)
        p[e] = g1 * Wg2[lane * NEXP + e] + g2 * Wg2[(64 + lane) * NEXP + e];
#pragma unroll
    for (int off = 32; off > 0; off >>= 1)
#pragma unroll
        for (int e = 0; e < NEXP; ++e) p[e] += __shfl_xor(p[e], off, 64);
    if (lane == 0) {
        float l[NEXP], mx = -1e30f;
#pragma unroll
        for (int e = 0; e < NEXP; ++e) { l[e] = p[e] + bg2[e]; mx = fmaxf(mx, l[e]); }
        float pr[NEXP], s = 0.f;
#pragma unroll
        for (int e = 0; e < NEXP; ++e) { pr[e] = expf(l[e] - mx); s += pr[e]; }
#pragma unroll
        for (int e = 0; e < NEXP; ++e) pr[e] /= s;
        int i0 = 0;
#pragma unroll
        for (int e = 1; e < NEXP; ++e) if (pr[e] > pr[i0]) i0 = e;
        int i1 = -1;
#pragma unroll
        for (int e = 0; e < NEXP; ++e) if (e != i0 && (i1 < 0 || pr[e] > pr[i1])) i1 = e;
        float v0 = pr[i0], v1 = pr[i1], s2 = v0 + v1;
        gates[2 * n]     = v0 / s2;
        gates[2 * n + 1] = v1 / s2;
        esel[2 * n]      = i0;
        esel[2 * n + 1]  = i1;
    }
}

// ---------- MFMA GEMM: C(M x 512) = A(M x KD, fp32) * B(KD x 512) given as Bt(512 x KD, bf16) ----------
// wave computes 16x16 tile. MODE 0: store; 1: gelu(acc+bias); 2: routed accumulate; 3: relu(acc+msg)
template<int KD, int MODE>
__global__ __launch_bounds__(256) void gemm16(
    const float* __restrict__ A, const unsigned short* __restrict__ Bt,
    float* C, const float* __restrict__ bias, const float* msg,
    const float* __restrict__ gates, const int* __restrict__ esel, int eid) {
    int w = threadIdx.x >> 6, lane = threadIdx.x & 63;
    int ln = lane & 15, q = lane >> 4;
    int n0 = blockIdx.x * 64 + w * 16;
    int m0 = blockIdx.y * 16;
    const float*          ap = A  + (size_t)(m0 + ln) * KD + q * 8;
    const unsigned short* bp = Bt + (size_t)(n0 + ln) * KD + q * 8;
    float4v acc = {0.f, 0.f, 0.f, 0.f};
#pragma unroll
    for (int k = 0; k < KD; k += 32) {
        float4v a0 = *(const float4v*)(ap + k);
        float4v a1 = *(const float4v*)(ap + k + 4);
        union { short8 v; __hip_bfloat162 h[4]; } ua;
        ua.h[0] = __float22bfloat162_rn(make_float2(a0[0], a0[1]));
        ua.h[1] = __float22bfloat162_rn(make_float2(a0[2], a0[3]));
        ua.h[2] = __float22bfloat162_rn(make_float2(a1[0], a1[1]));
        ua.h[3] = __float22bfloat162_rn(make_float2(a1[2], a1[3]));
        short8 bv = __builtin_bit_cast(short8, *(const float4v*)(bp + k));
        acc = __builtin_amdgcn_mfma_f32_16x16x32_bf16(ua.v, bv, acc, 0, 0, 0);
    }
    int col = n0 + ln;
    float bcol = (MODE == 1 || MODE == 2) ? bias[col] : 0.f;
    if (MODE == 2) {
#pragma unroll
        for (int r = 0; r < 4; ++r) {
            int row = m0 + q * 4 + r;
            int e0 = esel[2 * row], e1 = esel[2 * row + 1];
            float gt = (e0 == eid) ? gates[2 * row] : ((e1 == eid) ? gates[2 * row + 1] : 0.f);
            if (gt != 0.f) {
                size_t o = (size_t)row * HDIM + col;
                C[o] += gt * (acc[r] + bcol);
            }
        }
    } else {
#pragma unroll
        for (int r = 0; r < 4; ++r) {
            int row = m0 + q * 4 + r;
            size_t o = (size_t)row * HDIM + col;
            float v = acc[r];
            if (MODE == 1) v = gelu_tanh(v + bcol);
            if (MODE == 3) v = fmaxf(v + msg[o], 0.f);
            C[o] = v;
        }
    }
}

// ---------- CSR build + segment-sum ----------
__global__ void hist_kernel(const int* __restrict__ dst, int* __restrict__ deg) {
    int i = blockIdx.x * blockDim.x + threadIdx.x;
    if (i < NEDGE) atomicAdd(&deg[dst[i]], 1);
}
__global__ void scan_block(const int* __restrict__ in, int* __restrict__ incl,
                           int* __restrict__ bsum, int n) {
    __shared__ int s[256];
    int i = blockIdx.x * 256 + threadIdx.x;
    s[threadIdx.x] = (i < n) ? in[i] : 0;
    __syncthreads();
    for (int off = 1; off < 256; off <<= 1) {
        int t = (threadIdx.x >= (unsigned)off) ? s[threadIdx.x - off] : 0;
        __syncthreads();
        s[threadIdx.x] += t;
        __syncthreads();
    }
    if (i < n) incl[i] = s[threadIdx.x];
    if (bsum != nullptr && threadIdx.x == 255) bsum[blockIdx.x] = s[255];
}
__global__ void scan_fix(const int* __restrict__ incl, const int* __restrict__ deg,
                         const int* __restrict__ bscan, int* __restrict__ rowstart,
                         int* __restrict__ cursor) {
    int i = blockIdx.x * blockDim.x + threadIdx.x;
    if (i < NNODE) {
        int b = i >> 8;
        int add = (b > 0) ? bscan[b - 1] : 0;
        int st = incl[i] - deg[i] + add;
        rowstart[i] = st;
        cursor[i] = st;
    }
}
__global__ void fill_csr(const int* __restrict__ src, const int* __restrict__ dst,
                         int* __restrict__ cursor, int* __restrict__ srcs) {
    int e = blockIdx.x * blockDim.x + threadIdx.x;
    if (e < NEDGE) {
        int pos = atomicAdd(&cursor[dst[e]], 1);
        srcs[pos] = src[e];
    }
}
// block = 128 threads, one block per dst node; thread owns 4 consecutive cols.
__global__ __launch_bounds__(128) void msg_sum(
    const float* __restrict__ t1, const int* __restrict__ rowstart, const int* __restrict__ deg,
    const int* __restrict__ srcs, float* __restrict__ msg) {
    int n = blockIdx.x;
    int c0 = threadIdx.x * 4;
    int st = rowstart[n], d = deg[n];
    float4v acc = {0.f, 0.f, 0.f, 0.f};
    for (int t = 0; t < d; ++t) {
        int s = srcs[st + t];
        float4v v = *(const float4v*)(t1 + (size_t)s * HDIM + c0);
        acc[0] += v[0]; acc[1] += v[1]; acc[2] += v[2]; acc[3] += v[3];
    }
    *(float4v*)(msg + (size_t)n * HDIM + c0) = acc;
}

extern "C" void kernel_launch(void* const* d_in, const int* in_sizes, int n_in,
                              void* d_out, int out_size, void* d_ws, size_t ws_size,
                              hipStream_t stream) {
    (void)in_sizes; (void)n_in; (void)out_size; (void)ws_size;
    const float* text       = (const float*)d_in[0];
    const float* tabular    = (const float*)d_in[1];
    const float* structured = (const float*)d_in[2];
    const int*   e_in       = (const int*)d_in[3];
    const float* Wg1  = (const float*)d_in[4];
    const float* bg1  = (const float*)d_in[5];
    const float* Wg2  = (const float*)d_in[6];
    const float* bg2  = (const float*)d_in[7];
    const float* We1  = (const float*)d_in[8];
    const float* be1  = (const float*)d_in[9];
    const float* We2  = (const float*)d_in[10];
    const float* be2  = (const float*)d_in[11];
    const float* Wself = (const float*)d_in[12];
    const float* Wnbr  = (const float*)d_in[13];
    const int* src = e_in;
    const int* dst = e_in + NEDGE;
    float* dout = (float*)d_out;

    // workspace carve-up
    char* w = (char*)d_ws;
    auto alloc = [&](size_t bytes) { char* p = w; w += (bytes + 511) & ~(size_t)511; return p; };
    unsigned short* We1t   = (unsigned short*)alloc((size_t)NEXP * HDIM * EDIM * 2);
    unsigned short* We2t   = (unsigned short*)alloc((size_t)NEXP * HDIM * HDIM * 2);
    unsigned short* Wnbrt  = (unsigned short*)alloc((size_t)2 * HDIM * HDIM * 2);
    unsigned short* Wselft = (unsigned short*)alloc((size_t)2 * HDIM * HDIM * 2);
    float* gates   = (float*)alloc((size_t)NNODE * 2 * 4);
    int*   esel    = (int*)alloc((size_t)NNODE * 2 * 4);
    int*   deg     = (int*)alloc((size_t)NNODE * 4);
    int*   incl    = (int*)alloc((size_t)NNODE * 4);
    int*   bsum    = (int*)alloc(256 * 4);
    int*   bscan   = (int*)alloc(256 * 4);
    int*   rowstart= (int*)alloc((size_t)NNODE * 4);
    int*   cursor  = (int*)alloc((size_t)NNODE * 4);
    int*   srcs    = (int*)alloc((size_t)NEDGE * 4);
    float* buf1    = (float*)alloc((size_t)NNODE * HDIM * 4);  // g -> h1 -> t1/h ping
    float* nf      = (float*)alloc((size_t)NNODE * HDIM * 4);  // node_feats / h ping

    // weights -> bf16 transposed
    wtrans<<<2048, 256, 0, stream>>>(We1,   We1t,   NEXP, EDIM, HDIM);
    wtrans<<<2048, 256, 0, stream>>>(We2,   We2t,   NEXP, HDIM, HDIM);
    wtrans<<<2048, 256, 0, stream>>>(Wself, Wselft, 2,    HDIM, HDIM);
    wtrans<<<2048, 256, 0, stream>>>(Wnbr,  Wnbrt,  2,    HDIM, HDIM);

    hipMemsetAsync(nf, 0, (size_t)NNODE * HDIM * 4, stream);
    hipMemsetAsync(deg, 0, (size_t)NNODE * 4, stream);

    // gate (fp32) + top-2 routing
    gate_gemm<<<NNODE / 16, 256, 0, stream>>>(text, tabular, structured, Wg1, bg1, buf1);
    gating<<<NNODE / 4, 256, 0, stream>>>(buf1, Wg2, bg2, gates, esel);

    // experts: dense compute, routed accumulate into nf
    dim3 g16(HDIM / 64, NNODE / 16);
    const float* xin[NEXP] = { tabular, structured, text, text, structured };
    for (int e = 0; e < NEXP; ++e) {
        gemm16<EDIM, 1><<<g16, 256, 0, stream>>>(xin[e], We1t + (size_t)e * HDIM * EDIM, buf1,
                                                 be1 + e * HDIM, nullptr, nullptr, nullptr, 0);
        gemm16<HDIM, 2><<<g16, 256, 0, stream>>>(buf1, We2t + (size_t)e * HDIM * HDIM, nf,
                                                 be2 + e * HDIM, nullptr, gates, esel, e);
    }

    // CSR of edges grouped by dst
    const int NB = (NNODE + 255) / 256;
    hist_kernel<<<(NEDGE + 255) / 256, 256, 0, stream>>>(dst, deg);
    scan_block<<<NB, 256, 0, stream>>>(deg, incl, bsum, NNODE);
    scan_block<<<1, 256, 0, stream>>>(bsum, bscan, nullptr, NB);
    scan_fix<<<NB, 256, 0, stream>>>(incl, deg, bscan, rowstart, cursor);
    fill_csr<<<(NEDGE + 255) / 256, 256, 0, stream>>>(src, dst, cursor, srcs);

    // GNN layer 0: h = nf -> buf1
    gemm16<HDIM, 0><<<g16, 256, 0, stream>>>(nf, Wnbrt, buf1, nullptr, nullptr, nullptr, nullptr, 0);
    msg_sum<<<NNODE, 128, 0, stream>>>(buf1, rowstart, deg, srcs, dout);
    gemm16<HDIM, 3><<<g16, 256, 0, stream>>>(nf, Wselft, buf1, nullptr, dout, nullptr, nullptr, 0);

    // GNN layer 1: h = buf1 -> dout
    gemm16<HDIM, 0><<<g16, 256, 0, stream>>>(buf1, Wnbrt + (size_t)HDIM * HDIM, nf,
                                             nullptr, nullptr, nullptr, nullptr, 0);
    msg_sum<<<NNODE, 128, 0, stream>>>(nf, rowstart, deg, srcs, dout);
    gemm16<HDIM, 3><<<g16, 256, 0, stream>>>(buf1, Wselft + (size_t)HDIM * HDIM, dout,
                                             nullptr, dout, nullptr, nullptr, 0);
}

// Round 2
// 2085.098 us; speedup vs baseline: 3.6516x; 3.6516x over previous
//
#include <hip/hip_runtime.h>
#include <hip/hip_bf16.h>

#define NNODE 50000
#define M_PAD 50048
#define EDIM  256
#define HDIM  512
#define NEXP  5
#define GHID  128
#define NEDGE 800000

typedef __attribute__((ext_vector_type(8))) short  short8;
typedef __attribute__((ext_vector_type(4))) float  float4v;
typedef __attribute__((ext_vector_type(4))) unsigned short ushort4v;

typedef __attribute__((address_space(1))) const unsigned int gas_u32;
typedef __attribute__((address_space(3))) unsigned int       las_u32;

__device__ __forceinline__ void gl_lds16(const unsigned short* g, unsigned short* l) {
    __builtin_amdgcn_global_load_lds((gas_u32*)g, (las_u32*)l, 16, 0, 0);
}

__device__ __forceinline__ unsigned short f2b(float f) {
    unsigned u = __builtin_bit_cast(unsigned, f);
    u += 0x7FFFu + ((u >> 16) & 1u);
    return (unsigned short)(u >> 16);
}
__device__ __forceinline__ float b2f(unsigned short h) {
    unsigned u = ((unsigned)h) << 16;
    return __builtin_bit_cast(float, u);
}

__device__ __forceinline__ float fast_tanh(float y) {
    float ay = fabsf(y);
    float e  = __expf(-2.0f * ay);
    float t  = (1.0f - e) / (1.0f + e);
    return (y < 0.0f) ? -t : t;
}
__device__ __forceinline__ float gelu_tanh(float x) {
    float inner = 0.7978845608028654f * (x + 0.044715f * x * x * x);
    return 0.5f * x * (1.0f + fast_tanh(inner));
}

// ---------- weight transpose + fp32->bf16 (out[b][c][r] = bf16(in[b][r][c])) ----------
__global__ void wtrans(const float* __restrict__ in, unsigned short* __restrict__ out,
                       int B, int R, int C) {
    int total = B * R * C;
    for (int i = blockIdx.x * blockDim.x + threadIdx.x; i < total; i += gridDim.x * blockDim.x) {
        int rc  = R * C;
        int b   = i / rc;
        int rem = i - b * rc;
        int c   = rem / R;
        int r   = rem - c * R;
        out[i] = f2b(in[(size_t)b * rc + (size_t)r * C + c]);
    }
}

// ---------- activation fp32 -> bf16, pad rows [NNODE, M_PAD) with zeros ----------
__global__ void cvt_pad(const float* __restrict__ in, unsigned short* __restrict__ out,
                        int colshift) {
    int nv = (M_PAD << colshift) >> 2;
    for (int i = blockIdx.x * blockDim.x + threadIdx.x; i < nv; i += gridDim.x * blockDim.x) {
        int e0  = i << 2;
        int row = e0 >> colshift;
        ushort4v o;
        if (row < NNODE) {
            float4v v = *(const float4v*)(in + e0);
            o[0] = f2b(v[0]); o[1] = f2b(v[1]); o[2] = f2b(v[2]); o[3] = f2b(v[3]);
        } else {
            o[0] = 0; o[1] = 0; o[2] = 0; o[3] = 0;
        }
        *(ushort4v*)(out + e0) = o;
    }
}

// ---------- gate GEMM: g = relu(concat(text,tab,str) @ Wg1 + bg1), fp32 ----------
__global__ __launch_bounds__(256) void gate_gemm(
    const float* __restrict__ text, const float* __restrict__ tab, const float* __restrict__ str,
    const float* __restrict__ Wg1, const float* __restrict__ bg1, float* __restrict__ g) {
    int jg = threadIdx.x & 31;
    int rp = threadIdx.x >> 5;
    int r0 = blockIdx.x * 16 + rp * 2;
    float acc[2][4] = {{0.f,0.f,0.f,0.f},{0.f,0.f,0.f,0.f}};
    const float* xsrc[3] = { text, tab, str };
    for (int part = 0; part < 3; ++part) {
        const float* x0 = xsrc[part] + (size_t)r0 * EDIM;
        const float* wp = Wg1 + (size_t)part * EDIM * GHID + 4 * jg;
        for (int k = 0; k < EDIM; k += 4) {
            float4v xa = *(const float4v*)(x0 + k);
            float4v xb = *(const float4v*)(x0 + EDIM + k);
            float4v w0 = *(const float4v*)(wp + (size_t)(k + 0) * GHID);
            float4v w1 = *(const float4v*)(wp + (size_t)(k + 1) * GHID);
            float4v w2 = *(const float4v*)(wp + (size_t)(k + 2) * GHID);
            float4v w3 = *(const float4v*)(wp + (size_t)(k + 3) * GHID);
#pragma unroll
            for (int c = 0; c < 4; ++c) {
                acc[0][c] += xa[0]*w0[c] + xa[1]*w1[c] + xa[2]*w2[c] + xa[3]*w3[c];
                acc[1][c] += xb[0]*w0[c] + xb[1]*w1[c] + xb[2]*w2[c] + xb[3]*w3[c];
            }
        }
    }
    int j = 4 * jg;
#pragma unroll
    for (int rr = 0; rr < 2; ++rr) {
        float4v o;
#pragma unroll
        for (int c = 0; c < 4; ++c) o[c] = fmaxf(acc[rr][c] + bg1[j + c], 0.0f);
        *(float4v*)(g + (size_t)(r0 + rr) * GHID + j) = o;
    }
}

// ---------- gating: logits -> softmax -> top2 -> normalized gates (fp32) ----------
__global__ __launch_bounds__(256) void gating(
    const float* __restrict__ g, const float* __restrict__ Wg2, const float* __restrict__ bg2,
    float* __restrict__ gates, int* __restrict__ esel) {
    int wv = threadIdx.x >> 6, lane = threadIdx.x & 63;
    int n = blockIdx.x * 4 + wv;
    float p[NEXP];
    float g1 = g[(size_t)n * GHID + lane];
    float g2 = g[(size_t)n * GHID + 64 + lane];
#pragma unroll
    for (int e = 0; e < NEXP; ++e)
        p[e] = g1 * Wg2[lane * NEXP + e] + g2 * Wg2[(64 + lane) * NEXP + e];
#pragma unroll
    for (int off = 32; off > 0; off >>= 1)
#pragma unroll
        for (int e = 0; e < NEXP; ++e) p[e] += __shfl_xor(p[e], off, 64);
    if (lane == 0) {
        float l[NEXP], mx = -1e30f;
#pragma unroll
        for (int e = 0; e < NEXP; ++e) { l[e] = p[e] + bg2[e]; mx = fmaxf(mx, l[e]); }
        float pr[NEXP], s = 0.f;
#pragma unroll
        for (int e = 0; e < NEXP; ++e) { pr[e] = expf(l[e] - mx); s += pr[e]; }
#pragma unroll
        for (int e = 0; e < NEXP; ++e) pr[e] /= s;
        int i0 = 0;
#pragma unroll
        for (int e = 1; e < NEXP; ++e) if (pr[e] > pr[i0]) i0 = e;
        int i1 = -1;
#pragma unroll
        for (int e = 0; e < NEXP; ++e) if (e != i0 && (i1 < 0 || pr[e] > pr[i1])) i1 = e;
        float v0 = pr[i0], v1 = pr[i1], s2 = v0 + v1;
        gates[2 * n]     = v0 / s2;
        gates[2 * n + 1] = v1 / s2;
        esel[2 * n]      = i0;
        esel[2 * n + 1]  = i1;
    }
}

// ---------- tiled MFMA GEMM: C(M_PAD x 512) = A(M_PAD x K, bf16) * Bt(512 x K, bf16)^T ----------
// 128x128 block tile, 4 waves (2x2), each wave 64x64 via 4x4 16x16x32 frags.
// BK=64 staged in LDS via global_load_lds(16B) with XOR k-group swizzle on the
// GLOBAL source address (LDS dest of global_load_lds is fixed wave-base+lane*16).
// MODE: 0 = bf16(gelu(acc+bias))      (expert layer 1)
//       1 = routed bf16 accumulate    (expert layer 2: nfb += gate*(acc+bias))
//       2 = bf16(acc)                 (GNN msg transform)
//       3 = bf16(relu(acc+msg))       (GNN layer 0 output)
//       4 = f32  relu(acc+msg), guarded row<NNODE (final output)
template<int K, int MODE>
__global__ __launch_bounds__(256) void gemm128(
    const unsigned short* __restrict__ A, const unsigned short* __restrict__ Bt,
    unsigned short* __restrict__ Cb, float* __restrict__ Cf,
    const float* __restrict__ bias, const float* __restrict__ msg,
    const float* __restrict__ gates, const int* __restrict__ esel, int eid) {
    __shared__ unsigned short As[128 * 64];
    __shared__ unsigned short Bs[128 * 64];
    const int t = threadIdx.x;
    const int w = t >> 6, lane = t & 63;
    const int ln = lane & 15, q = lane >> 4;
    const int wm = (w >> 1) * 64, wn = (w & 1) * 64;

    // staging: thread covers (row rb + 32*it, k-group kg); global k swizzled by row&7
    const int rb = w * 8 + (lane >> 3);
    const int kg = lane & 7;
    const int koff = (kg ^ (rb & 7)) * 8;
    const unsigned short* Ag = A  + (size_t)(blockIdx.y * 128 + rb) * K + koff;
    const unsigned short* Bg = Bt + (size_t)(blockIdx.x * 128 + rb) * K + koff;
    unsigned short* Al = &As[rb * 64 + kg * 8];
    unsigned short* Bl = &Bs[rb * 64 + kg * 8];

    float4v acc[4][4];
#pragma unroll
    for (int i = 0; i < 4; ++i)
#pragma unroll
        for (int j = 0; j < 4; ++j) acc[i][j] = (float4v){0.f, 0.f, 0.f, 0.f};

    for (int kt = 0; kt < K; kt += 64) {
        __syncthreads();
#pragma unroll
        for (int it = 0; it < 4; ++it) {
            gl_lds16(Ag + (size_t)it * 32 * K + kt, Al + it * 32 * 64);
            gl_lds16(Bg + (size_t)it * 32 * K + kt, Bl + it * 32 * 64);
        }
        __syncthreads();
#pragma unroll
        for (int kk = 0; kk < 2; ++kk) {
            short8 af[4], bf[4];
#pragma unroll
            for (int i = 0; i < 4; ++i)
                af[i] = *(const short8*)&As[(wm + 16 * i + ln) * 64 + (((kk * 4 + q) ^ (ln & 7)) * 8)];
#pragma unroll
            for (int j = 0; j < 4; ++j)
                bf[j] = *(const short8*)&Bs[(wn + 16 * j + ln) * 64 + (((kk * 4 + q) ^ (ln & 7)) * 8)];
#pragma unroll
            for (int i = 0; i < 4; ++i)
#pragma unroll
                for (int j = 0; j < 4; ++j)
                    acc[i][j] = __builtin_amdgcn_mfma_f32_16x16x32_bf16(af[i], bf[j], acc[i][j], 0, 0, 0);
        }
    }

    const int gm0 = blockIdx.y * 128 + wm;
    const int gn0 = blockIdx.x * 128 + wn;

    if (MODE == 1) {
#pragma unroll
        for (int i = 0; i < 4; ++i) {
#pragma unroll
            for (int r = 0; r < 4; ++r) {
                int gm = gm0 + 16 * i + q * 4 + r;
                int e0 = esel[2 * gm], e1 = esel[2 * gm + 1];
                float gt = (e0 == eid) ? gates[2 * gm] : ((e1 == eid) ? gates[2 * gm + 1] : 0.f);
                if (gt != 0.f) {
#pragma unroll
                    for (int j = 0; j < 4; ++j) {
                        int gn = gn0 + 16 * j + ln;
                        size_t o = (size_t)gm * HDIM + gn;
                        Cb[o] = f2b(b2f(Cb[o]) + gt * (acc[i][j][r] + bias[gn]));
                    }
                }
            }
        }
    } else {
#pragma unroll
        for (int i = 0; i < 4; ++i) {
#pragma unroll
            for (int j = 0; j < 4; ++j) {
                int gn = gn0 + 16 * j + ln;
                float bcol = (MODE == 0) ? bias[gn] : 0.f;
#pragma unroll
                for (int r = 0; r < 4; ++r) {
                    int gm = gm0 + 16 * i + q * 4 + r;
                    size_t o = (size_t)gm * HDIM + gn;
                    float v = acc[i][j][r];
                    if (MODE == 0) { Cb[o] = f2b(gelu_tanh(v + bcol)); }
                    if (MODE == 2) { Cb[o] = f2b(v); }
                    if (MODE == 3) { Cb[o] = f2b(fmaxf(v + msg[o], 0.f)); }
                    if (MODE == 4) { if (gm < NNODE) Cf[o] = fmaxf(v + msg[o], 0.f); }
                }
            }
        }
    }
}

// ---------- CSR build ----------
__global__ void hist_kernel(const int* __restrict__ dst, int* __restrict__ deg) {
    int i = blockIdx.x * blockDim.x + threadIdx.x;
    if (i < NEDGE) atomicAdd(&deg[dst[i]], 1);
}
__global__ void scan_block(const int* __restrict__ in, int* __restrict__ incl,
                           int* __restrict__ bsum, int n) {
    __shared__ int s[256];
    int i = blockIdx.x * 256 + threadIdx.x;
    s[threadIdx.x] = (i < n) ? in[i] : 0;
    __syncthreads();
    for (int off = 1; off < 256; off <<= 1) {
        int t = (threadIdx.x >= (unsigned)off) ? s[threadIdx.x - off] : 0;
        __syncthreads();
        s[threadIdx.x] += t;
        __syncthreads();
    }
    if (i < n) incl[i] = s[threadIdx.x];
    if (bsum != nullptr && threadIdx.x == 255) bsum[blockIdx.x] = s[255];
}
__global__ void scan_fix(const int* __restrict__ incl, const int* __restrict__ deg,
                         const int* __restrict__ bscan, int* __restrict__ rowstart,
                         int* __restrict__ cursor) {
    int i = blockIdx.x * blockDim.x + threadIdx.x;
    if (i < NNODE) {
        int b = i >> 8;
        int add = (b > 0) ? bscan[b - 1] : 0;
        int st = incl[i] - deg[i] + add;
        rowstart[i] = st;
        cursor[i] = st;
    }
}
__global__ void fill_csr(const int* __restrict__ src, const int* __restrict__ dst,
                         int* __restrict__ cursor, int* __restrict__ srcs) {
    int e = blockIdx.x * blockDim.x + threadIdx.x;
    if (e < NEDGE) {
        int pos = atomicAdd(&cursor[dst[e]], 1);
        srcs[pos] = src[e];
    }
}

// ---------- segment-sum over bf16 rows: msg[n] = sum_{s in nbrs(n)} t1[s] ----------
// one block (4 waves) per dst node; lane owns 8 cols (16 B); waves split neighbors.
__global__ __launch_bounds__(256) void msg_sum_b(
    const unsigned short* __restrict__ t1, const int* __restrict__ rowstart,
    const int* __restrict__ deg, const int* __restrict__ srcs, float* __restrict__ msg) {
    __shared__ float sm[4][HDIM];
    int n = blockIdx.x;
    int wv = threadIdx.x >> 6, lane = threadIdx.x & 63;
    int st = rowstart[n], d = deg[n];
    float acc[8] = {0.f,0.f,0.f,0.f,0.f,0.f,0.f,0.f};
    for (int t = wv; t < d; t += 4) {
        int s = srcs[st + t];
        short8 v = *(const short8*)(t1 + (size_t)s * HDIM + lane * 8);
#pragma unroll
        for (int c = 0; c < 8; ++c) acc[c] += b2f((unsigned short)v[c]);
    }
#pragma unroll
    for (int c = 0; c < 8; ++c) sm[wv][lane * 8 + c] = acc[c];
    __syncthreads();
    if (threadIdx.x < 128) {
        int c0 = threadIdx.x * 4;
        float4v o;
#pragma unroll
        for (int c = 0; c < 4; ++c)
            o[c] = sm[0][c0 + c] + sm[1][c0 + c] + sm[2][c0 + c] + sm[3][c0 + c];
        *(float4v*)(msg + (size_t)n * HDIM + c0) = o;
    }
}

extern "C" void kernel_launch(void* const* d_in, const int* in_sizes, int n_in,
                              void* d_out, int out_size, void* d_ws, size_t ws_size,
                              hipStream_t stream) {
    (void)in_sizes; (void)n_in; (void)out_size; (void)ws_size;
    const float* text       = (const float*)d_in[0];
    const float* tabular    = (const float*)d_in[1];
    const float* structured = (const float*)d_in[2];
    const int*   e_in       = (const int*)d_in[3];
    const float* Wg1  = (const float*)d_in[4];
    const float* bg1  = (const float*)d_in[5];
    const float* Wg2  = (const float*)d_in[6];
    const float* bg2  = (const float*)d_in[7];
    const float* We1  = (const float*)d_in[8];
    const float* be1  = (const float*)d_in[9];
    const float* We2  = (const float*)d_in[10];
    const float* be2  = (const float*)d_in[11];
    const float* Wself = (const float*)d_in[12];
    const float* Wnbr  = (const float*)d_in[13];
    const int* src = e_in;
    const int* dst = e_in + NEDGE;
    float* dout = (float*)d_out;

    // ---- workspace carve-up ----
    char* w = (char*)d_ws;
    auto alloc = [&](size_t bytes) { char* p = w; w += (bytes + 511) & ~(size_t)511; return p; };
    const size_t SZ_Xb  = (size_t)M_PAD * EDIM * 2;   // 25.6 MB
    const size_t SZ_H   = (size_t)M_PAD * HDIM * 2;   // 51.2 MB
    const size_t SZ_MSG = (size_t)M_PAD * HDIM * 4;   // 102.5 MB
    const size_t SZ_G   = (size_t)NNODE * GHID * 4;   // 25.6 MB

    unsigned short* We1t   = (unsigned short*)alloc((size_t)NEXP * HDIM * EDIM * 2);
    unsigned short* We2t   = (unsigned short*)alloc((size_t)NEXP * HDIM * HDIM * 2);
    unsigned short* Wnbrt  = (unsigned short*)alloc((size_t)2 * HDIM * HDIM * 2);
    unsigned short* Wselft = (unsigned short*)alloc((size_t)2 * HDIM * HDIM * 2);
    float* gates    = (float*)alloc((size_t)M_PAD * 2 * 4);
    int*   esel     = (int*)alloc((size_t)M_PAD * 2 * 4);
    int*   deg      = (int*)alloc((size_t)NNODE * 4);
    int*   incl     = (int*)alloc((size_t)NNODE * 4);
    int*   bsum     = (int*)alloc(1024 * 4);
    int*   bscan    = (int*)alloc(1024 * 4);
    int*   rowstart = (int*)alloc((size_t)NNODE * 4);
    int*   cursor   = (int*)alloc((size_t)NNODE * 4);
    int*   srcs     = (int*)alloc((size_t)NEDGE * 4);
    unsigned short* nfb = (unsigned short*)alloc(SZ_H);
    size_t poolA = 3 * SZ_Xb + SZ_H + SZ_G;
    size_t poolB = 2 * SZ_H + SZ_MSG;
    char* pool = (char*)alloc(poolA > poolB ? poolA : poolB);
    // phase A (gate + experts)
    unsigned short* Xb0  = (unsigned short*)(pool);                       // tabular
    unsigned short* Xb1  = (unsigned short*)(pool + SZ_Xb);               // structured
    unsigned short* Xb2  = (unsigned short*)(pool + 2 * SZ_Xb);           // text
    unsigned short* h1b  = (unsigned short*)(pool + 3 * SZ_Xb);
    float*          gbuf = (float*)(pool + 3 * SZ_Xb + SZ_H);
    // phase B (GNN)
    unsigned short* t1b = (unsigned short*)(pool);
    unsigned short* hb  = (unsigned short*)(pool + SZ_H);
    float*          msg = (float*)(pool + 2 * SZ_H);

    // ---- weights -> bf16 transposed (Bt layout: [out_col][k]) ----
    wtrans<<<2048, 256, 0, stream>>>(We1,   We1t,   NEXP, EDIM, HDIM);
    wtrans<<<2048, 256, 0, stream>>>(We2,   We2t,   NEXP, HDIM, HDIM);
    wtrans<<<2048, 256, 0, stream>>>(Wself, Wselft, 2,    HDIM, HDIM);
    wtrans<<<2048, 256, 0, stream>>>(Wnbr,  Wnbrt,  2,    HDIM, HDIM);

    // ---- activations -> bf16 padded ----
    cvt_pad<<<1280, 256, 0, stream>>>(tabular,    Xb0, 8);
    cvt_pad<<<1280, 256, 0, stream>>>(structured, Xb1, 8);
    cvt_pad<<<1280, 256, 0, stream>>>(text,       Xb2, 8);

    hipMemsetAsync(nfb, 0, SZ_H, stream);
    hipMemsetAsync(deg, 0, (size_t)NNODE * 4, stream);
    // pad rows of esel -> -1 so routed epilogue never matches them
    hipMemsetAsync(esel + NNODE * 2, 0xFF, (size_t)(M_PAD - NNODE) * 2 * 4, stream);

    // ---- gate (fp32) + top-2 routing ----
    gate_gemm<<<NNODE / 16, 256, 0, stream>>>(text, tabular, structured, Wg1, bg1, gbuf);
    gating<<<NNODE / 4, 256, 0, stream>>>(gbuf, Wg2, bg2, gates, esel);

    // ---- experts: dense compute, routed bf16 accumulate into nfb ----
    dim3 g128(HDIM / 128, M_PAD / 128);
    const unsigned short* xin[NEXP] = { Xb0, Xb1, Xb2, Xb2, Xb1 };
    for (int e = 0; e < NEXP; ++e) {
        gemm128<EDIM, 0><<<g128, 256, 0, stream>>>(xin[e], We1t + (size_t)e * HDIM * EDIM,
                                                   h1b, nullptr, be1 + e * HDIM,
                                                   nullptr, nullptr, nullptr, 0);
        gemm128<HDIM, 1><<<g128, 256, 0, stream>>>(h1b, We2t + (size_t)e * HDIM * HDIM,
                                                   nfb, nullptr, be2 + e * HDIM,
                                                   nullptr, gates, esel, e);
    }

    // ---- CSR of edges grouped by dst ----
    const int NB = (NNODE + 255) / 256;
    hist_kernel<<<(NEDGE + 255) / 256, 256, 0, stream>>>(dst, deg);
    scan_block<<<NB, 256, 0, stream>>>(deg, incl, bsum, NNODE);
    scan_block<<<1, 256, 0, stream>>>(bsum, bscan, nullptr, NB);
    scan_fix<<<NB, 256, 0, stream>>>(incl, deg, bscan, rowstart, cursor);
    fill_csr<<<(NEDGE + 255) / 256, 256, 0, stream>>>(src, dst, cursor, srcs);

    // ---- GNN layer 0 ----
    gemm128<HDIM, 2><<<g128, 256, 0, stream>>>(nfb, Wnbrt, t1b, nullptr,
                                               nullptr, nullptr, nullptr, nullptr, 0);
    msg_sum_b<<<NNODE, 256, 0, stream>>>(t1b, rowstart, deg, srcs, msg);
    gemm128<HDIM, 3><<<g128, 256, 0, stream>>>(nfb, Wselft, hb, nullptr,
                                               nullptr, msg, nullptr, nullptr, 0);

    // ---- GNN layer 1 ----
    gemm128<HDIM, 2><<<g128, 256, 0, stream>>>(hb, Wnbrt + (size_t)HDIM * HDIM, t1b, nullptr,
                                               nullptr, nullptr, nullptr, nullptr, 0);
    msg_sum_b<<<NNODE, 256, 0, stream>>>(t1b, rowstart, deg, srcs, msg);
    gemm128<HDIM, 4><<<g128, 256, 0, stream>>>(hb, Wselft + (size_t)HDIM * HDIM, nullptr, dout,
                                               nullptr, msg, nullptr, nullptr, 0);
}

// Round 3
// 1117.845 us; speedup vs baseline: 6.8113x; 1.8653x over previous
//
#include <hip/hip_runtime.h>
#include <hip/hip_bf16.h>

#define NNODE 50000
#define M_PAD 50048
#define EDIM  256
#define HDIM  512
#define NEXP  5
#define GHID  128
#define NEDGE 800000
#define SLOTCAP 101504   // >= 2*NNODE + 10*127, 128-aligned
#define MAXT_ALL 792     // max (expert,rank) tiles total
#define MAXT_R   396     // max tiles per rank

typedef __attribute__((ext_vector_type(8))) short  short8;
typedef __attribute__((ext_vector_type(4))) float  float4v;
typedef __attribute__((ext_vector_type(4))) unsigned short ushort4v;

typedef __attribute__((address_space(1))) const unsigned int gas_u32;
typedef __attribute__((address_space(3))) unsigned int       las_u32;

__device__ __forceinline__ void gl_lds16(const unsigned short* g, unsigned short* l) {
    __builtin_amdgcn_global_load_lds((gas_u32*)g, (las_u32*)l, 16, 0, 0);
}
__device__ __forceinline__ unsigned short f2b(float f) {
    unsigned u = __builtin_bit_cast(unsigned, f);
    u += 0x7FFFu + ((u >> 16) & 1u);
    return (unsigned short)(u >> 16);
}
__device__ __forceinline__ float b2f(unsigned short h) {
    unsigned u = ((unsigned)h) << 16;
    return __builtin_bit_cast(float, u);
}
__device__ __forceinline__ float fast_tanh(float y) {
    float ay = fabsf(y);
    float e  = __expf(-2.0f * ay);
    float t  = (1.0f - e) / (1.0f + e);
    return (y < 0.0f) ? -t : t;
}
__device__ __forceinline__ float gelu_tanh(float x) {
    float inner = 0.7978845608028654f * (x + 0.044715f * x * x * x);
    return 0.5f * x * (1.0f + fast_tanh(inner));
}

// ---------- weight transpose helpers (Bt layout: [out_col][k], bf16) ----------
__global__ void wtrans(const float* __restrict__ in, unsigned short* __restrict__ out,
                       int B, int R, int C) {
    int total = B * R * C;
    for (int i = blockIdx.x * blockDim.x + threadIdx.x; i < total; i += gridDim.x * blockDim.x) {
        int rc  = R * C;
        int b   = i / rc;
        int rem = i - b * rc;
        int c   = rem / R;
        int r   = rem - c * R;
        out[i] = f2b(in[(size_t)b * rc + (size_t)r * C + c]);
    }
}
// single matrix with output leading-dim + k-offset (for concatenated B)
__global__ void wtrans_k(const float* __restrict__ in, unsigned short* __restrict__ out,
                         int R, int C, int ldo, int ko) {
    int total = R * C;
    for (int i = blockIdx.x * blockDim.x + threadIdx.x; i < total; i += gridDim.x * blockDim.x) {
        int c = i / R;
        int r = i - c * R;
        out[(size_t)c * ldo + ko + r] = f2b(in[(size_t)r * C + c]);
    }
}
// hi/lo split transpose (for the fp32-fidelity gate GEMM)
__global__ void wtrans2(const float* __restrict__ in, unsigned short* __restrict__ oh,
                        unsigned short* __restrict__ ol, int R, int C) {
    int total = R * C;
    for (int i = blockIdx.x * blockDim.x + threadIdx.x; i < total; i += gridDim.x * blockDim.x) {
        int c = i / R;
        int r = i - c * R;
        float f = in[(size_t)r * C + c];
        unsigned short h = f2b(f);
        oh[i] = h;
        ol[i] = f2b(f - b2f(h));
    }
}

// ---------- gate layer 1, bf16x3 split MFMA: g = relu(concat(text,tab,str) @ Wg1 + bg1) ----------
// 128x128 tile (GHID=128 = full N), K=768 over three fp32 sources, hi/lo staged manually.
__global__ __launch_bounds__(256) void gate128(
    const float* __restrict__ xtxt, const float* __restrict__ xtab, const float* __restrict__ xstr,
    const unsigned short* __restrict__ Bh, const unsigned short* __restrict__ Blo,
    const float* __restrict__ bg1, float* __restrict__ g) {
    __shared__ unsigned short Ash[128 * 64];
    __shared__ unsigned short Asl[128 * 64];
    __shared__ unsigned short Bsh[128 * 64];
    __shared__ unsigned short Bsl[128 * 64];
    const int t = threadIdx.x, w = t >> 6, lane = t & 63;
    const int ln = lane & 15, q = lane >> 4;
    const int wm = (w >> 1) * 64, wn = (w & 1) * 64;
    const int rb = w * 8 + (lane >> 3), kg = lane & 7;
    const int koff = (kg ^ (rb & 7)) * 8;
    const float* xs[3] = { xtxt, xtab, xstr };
    const unsigned short* Bgh = Bh  + (size_t)rb * 768 + koff;
    const unsigned short* Bgl = Blo + (size_t)rb * 768 + koff;
    unsigned short* Blh = &Bsh[rb * 64 + kg * 8];
    unsigned short* Bll = &Bsl[rb * 64 + kg * 8];
    float4v acc[4][4];
#pragma unroll
    for (int i = 0; i < 4; ++i)
#pragma unroll
        for (int j = 0; j < 4; ++j) acc[i][j] = (float4v){0.f, 0.f, 0.f, 0.f};

    for (int kt = 0; kt < 768; kt += 64) {
        const float* xp = xs[kt >> 8];
        const int kloc = kt & 255;
        __syncthreads();
#pragma unroll
        for (int it = 0; it < 4; ++it) {
            int row = blockIdx.y * 128 + rb + 32 * it;
            union { short8 v; unsigned short s[8]; } ph, pl;
            if (row < NNODE) {
                const float* sp = xp + (size_t)row * EDIM + kloc + koff;
                float4v a0 = *(const float4v*)sp;
                float4v a1 = *(const float4v*)(sp + 4);
#pragma unroll
                for (int c = 0; c < 4; ++c) {
                    unsigned short h0 = f2b(a0[c]);
                    ph.s[c] = h0; pl.s[c] = f2b(a0[c] - b2f(h0));
                    unsigned short h1 = f2b(a1[c]);
                    ph.s[4 + c] = h1; pl.s[4 + c] = f2b(a1[c] - b2f(h1));
                }
            } else {
#pragma unroll
                for (int c = 0; c < 8; ++c) { ph.s[c] = 0; pl.s[c] = 0; }
            }
            *(short8*)&Ash[(rb + 32 * it) * 64 + kg * 8] = ph.v;
            *(short8*)&Asl[(rb + 32 * it) * 64 + kg * 8] = pl.v;
            gl_lds16(Bgh + (size_t)it * 32 * 768 + kt, Blh + it * 32 * 64);
            gl_lds16(Bgl + (size_t)it * 32 * 768 + kt, Bll + it * 32 * 64);
        }
        __syncthreads();
#pragma unroll
        for (int kk = 0; kk < 2; ++kk) {
            short8 ah[4], al[4], bh[4], bl[4];
#pragma unroll
            for (int i = 0; i < 4; ++i) {
                int off = (wm + 16 * i + ln) * 64 + (((kk * 4 + q) ^ (ln & 7)) * 8);
                ah[i] = *(const short8*)&Ash[off];
                al[i] = *(const short8*)&Asl[off];
            }
#pragma unroll
            for (int j = 0; j < 4; ++j) {
                int off = (wn + 16 * j + ln) * 64 + (((kk * 4 + q) ^ (ln & 7)) * 8);
                bh[j] = *(const short8*)&Bsh[off];
                bl[j] = *(const short8*)&Bsl[off];
            }
#pragma unroll
            for (int i = 0; i < 4; ++i)
#pragma unroll
                for (int j = 0; j < 4; ++j) {
                    acc[i][j] = __builtin_amdgcn_mfma_f32_16x16x32_bf16(ah[i], bh[j], acc[i][j], 0, 0, 0);
                    acc[i][j] = __builtin_amdgcn_mfma_f32_16x16x32_bf16(ah[i], bl[j], acc[i][j], 0, 0, 0);
                    acc[i][j] = __builtin_amdgcn_mfma_f32_16x16x32_bf16(al[i], bh[j], acc[i][j], 0, 0, 0);
                }
        }
    }
    const int gm0 = blockIdx.y * 128 + wm;
#pragma unroll
    for (int i = 0; i < 4; ++i)
#pragma unroll
        for (int j = 0; j < 4; ++j) {
            int gn = wn + 16 * j + ln;
            float bc = bg1[gn];
#pragma unroll
            for (int r = 0; r < 4; ++r) {
                int gm = gm0 + 16 * i + q * 4 + r;
                g[(size_t)gm * GHID + gn] = fmaxf(acc[i][j][r] + bc, 0.f);
            }
        }
}

// ---------- gating: logits -> softmax -> top2 -> normalized gates (fp32) ----------
__global__ __launch_bounds__(256) void gating(
    const float* __restrict__ g, const float* __restrict__ Wg2, const float* __restrict__ bg2,
    float* __restrict__ gates, int* __restrict__ esel) {
    int wv = threadIdx.x >> 6, lane = threadIdx.x & 63;
    int n = blockIdx.x * 4 + wv;
    float p[NEXP];
    float g1 = g[(size_t)n * GHID + lane];
    float g2 = g[(size_t)n * GHID + 64 + lane];
#pragma unroll
    for (int e = 0; e < NEXP; ++e)
        p[e] = g1 * Wg2[lane * NEXP + e] + g2 * Wg2[(64 + lane) * NEXP + e];
#pragma unroll
    for (int off = 32; off > 0; off >>= 1)
#pragma unroll
        for (int e = 0; e < NEXP; ++e) p[e] += __shfl_xor(p[e], off, 64);
    if (lane == 0) {
        float l[NEXP], mx = -1e30f;
#pragma unroll
        for (int e = 0; e < NEXP; ++e) { l[e] = p[e] + bg2[e]; mx = fmaxf(mx, l[e]); }
        float pr[NEXP], s = 0.f;
#pragma unroll
        for (int e = 0; e < NEXP; ++e) { pr[e] = expf(l[e] - mx); s += pr[e]; }
#pragma unroll
        for (int e = 0; e < NEXP; ++e) pr[e] /= s;
        int i0 = 0;
#pragma unroll
        for (int e = 1; e < NEXP; ++e) if (pr[e] > pr[i0]) i0 = e;
        int i1 = -1;
#pragma unroll
        for (int e = 0; e < NEXP; ++e) if (e != i0 && (i1 < 0 || pr[e] > pr[i1])) i1 = e;
        float v0 = pr[i0], v1 = pr[i1], s2 = v0 + v1;
        gates[2 * n]     = v0 / s2;
        gates[2 * n + 1] = v1 / s2;
        esel[2 * n]      = i0;
        esel[2 * n + 1]  = i1;
    }
}

// ---------- slot machinery: per-(expert,rank) 128-padded compaction ----------
__global__ __launch_bounds__(256) void slot_count(const int* __restrict__ esel,
                                                  int* __restrict__ slotcnt) {
    __shared__ int h[10];
    if (threadIdx.x < 10) h[threadIdx.x] = 0;
    __syncthreads();
    int n = blockIdx.x * 256 + threadIdx.x;
    if (n < NNODE) {
        atomicAdd(&h[esel[2 * n] * 2 + 0], 1);
        atomicAdd(&h[esel[2 * n + 1] * 2 + 1], 1);
    }
    __syncthreads();
    if (threadIdx.x < 10) atomicAdd(&slotcnt[threadIdx.x], h[threadIdx.x]);
}
// header: [0]=tiles_all, [1]=tiles_rank0, [2]=tiles_rank1
__global__ void seg_plan(const int* __restrict__ slotcnt, int* __restrict__ cursor,
                         int* __restrict__ header, int2* __restrict__ meta_all,
                         int2* __restrict__ meta_r0, int2* __restrict__ meta_r1) {
    if (threadIdx.x == 0 && blockIdx.x == 0) {
        int base = 0, ta = 0, t0 = 0, t1 = 0;
        for (int s = 0; s < 10; ++s) {
            cursor[s] = base;
            int nt = (slotcnt[s] + 127) >> 7;
            for (int k = 0; k < nt; ++k) {
                int2 m; m.x = s; m.y = base + k * 128;
                meta_all[ta++] = m;
                if (s & 1) meta_r1[t1++] = m; else meta_r0[t0++] = m;
            }
            base += nt * 128;
        }
        header[0] = ta; header[1] = t0; header[2] = t1;
    }
}
__global__ __launch_bounds__(256) void slot_fill(
    const int* __restrict__ esel, const float* __restrict__ gates, int* __restrict__ cursor,
    int* __restrict__ rowlist, float* __restrict__ gateval) {
    __shared__ int h[10], base[10];
    if (threadIdx.x < 10) h[threadIdx.x] = 0;
    __syncthreads();
    int n = blockIdx.x * 256 + threadIdx.x;
    int s0 = 0, s1 = 0, p0 = 0, p1 = 0;
    bool on = (n < NNODE);
    if (on) {
        s0 = esel[2 * n] * 2;
        s1 = esel[2 * n + 1] * 2 + 1;
        p0 = atomicAdd(&h[s0], 1);
        p1 = atomicAdd(&h[s1], 1);
    }
    __syncthreads();
    if (threadIdx.x < 10) base[threadIdx.x] = atomicAdd(&cursor[threadIdx.x], h[threadIdx.x]);
    __syncthreads();
    if (on) {
        int q0 = base[s0] + p0, q1 = base[s1] + p1;
        rowlist[q0] = n; gateval[q0] = gates[2 * n];
        rowlist[q1] = n; gateval[q1] = gates[2 * n + 1];
    }
}

// ---------- expert layer 1 (compacted): h1[slot] = gelu(x[rowlist[slot]] @ We1[e] + be1[e]) ----------
__global__ __launch_bounds__(256) void gemm_moe1(
    const float* __restrict__ xtab, const float* __restrict__ xstr, const float* __restrict__ xtxt,
    const unsigned short* __restrict__ We1t, const float* __restrict__ be1,
    const int* __restrict__ header, const int2* __restrict__ meta,
    const int* __restrict__ rowlist, unsigned short* __restrict__ h1) {
    if ((int)blockIdx.y >= header[0]) return;
    __shared__ unsigned short As[128 * 64];
    __shared__ unsigned short Bs[128 * 64];
    int2 mt = meta[blockIdx.y];
    const int eid = mt.x >> 1, rowbase = mt.y;
    const float* xf = (eid == 0) ? xtab : ((eid == 1 || eid == 4) ? xstr : xtxt);
    const int t = threadIdx.x, w = t >> 6, lane = t & 63;
    const int ln = lane & 15, q = lane >> 4;
    const int wm = (w >> 1) * 64, wn = (w & 1) * 64;
    const int rb = w * 8 + (lane >> 3), kg = lane & 7;
    const int koff = (kg ^ (rb & 7)) * 8;
    int rows[4];
#pragma unroll
    for (int it = 0; it < 4; ++it) {
        int rr = rowlist[rowbase + rb + 32 * it];
        rows[it] = (rr < 0) ? 0 : rr;
    }
    const unsigned short* Bg = We1t + (size_t)eid * HDIM * EDIM
                             + (size_t)(blockIdx.x * 128 + rb) * EDIM + koff;
    unsigned short* Bl = &Bs[rb * 64 + kg * 8];
    float4v acc[4][4];
#pragma unroll
    for (int i = 0; i < 4; ++i)
#pragma unroll
        for (int j = 0; j < 4; ++j) acc[i][j] = (float4v){0.f, 0.f, 0.f, 0.f};

    for (int kt = 0; kt < EDIM; kt += 64) {
        __syncthreads();
#pragma unroll
        for (int it = 0; it < 4; ++it) {
            const float* sp = xf + (size_t)rows[it] * EDIM + kt + koff;
            float4v a0 = *(const float4v*)sp;
            float4v a1 = *(const float4v*)(sp + 4);
            union { short8 v; unsigned short s[8]; } pk;
#pragma unroll
            for (int c = 0; c < 4; ++c) { pk.s[c] = f2b(a0[c]); pk.s[4 + c] = f2b(a1[c]); }
            *(short8*)&As[(rb + 32 * it) * 64 + kg * 8] = pk.v;
            gl_lds16(Bg + (size_t)it * 32 * EDIM + kt, Bl + it * 32 * 64);
        }
        __syncthreads();
#pragma unroll
        for (int kk = 0; kk < 2; ++kk) {
            short8 af[4], bf[4];
#pragma unroll
            for (int i = 0; i < 4; ++i)
                af[i] = *(const short8*)&As[(wm + 16 * i + ln) * 64 + (((kk * 4 + q) ^ (ln & 7)) * 8)];
#pragma unroll
            for (int j = 0; j < 4; ++j)
                bf[j] = *(const short8*)&Bs[(wn + 16 * j + ln) * 64 + (((kk * 4 + q) ^ (ln & 7)) * 8)];
#pragma unroll
            for (int i = 0; i < 4; ++i)
#pragma unroll
                for (int j = 0; j < 4; ++j)
                    acc[i][j] = __builtin_amdgcn_mfma_f32_16x16x32_bf16(af[i], bf[j], acc[i][j], 0, 0, 0);
        }
    }
    const int gn0 = blockIdx.x * 128 + wn;
#pragma unroll
    for (int i = 0; i < 4; ++i)
#pragma unroll
        for (int j = 0; j < 4; ++j) {
            int gn = gn0 + 16 * j + ln;
            float bc = be1[eid * HDIM + gn];
#pragma unroll
            for (int r = 0; r < 4; ++r) {
                int slot = rowbase + wm + 16 * i + q * 4 + r;
                h1[(size_t)slot * HDIM + gn] = f2b(gelu_tanh(acc[i][j][r] + bc));
            }
        }
}

// ---------- expert layer 2 (compacted, scatter): nf[node] (+)= gate*(h1[slot]@We2[e] + be2[e]) ----------
template<int RMW>
__global__ __launch_bounds__(256) void gemm_moe2(
    const unsigned short* __restrict__ h1, const unsigned short* __restrict__ We2t,
    const float* __restrict__ be2, const int* __restrict__ header,
    const int2* __restrict__ meta, const int* __restrict__ rowlist,
    const float* __restrict__ gateval, unsigned short* __restrict__ nf) {
    if ((int)blockIdx.y >= header[RMW ? 2 : 1]) return;
    __shared__ unsigned short As[128 * 64];
    __shared__ unsigned short Bs[128 * 64];
    int2 mt = meta[blockIdx.y];
    const int eid = mt.x >> 1, rowbase = mt.y;
    const int t = threadIdx.x, w = t >> 6, lane = t & 63;
    const int ln = lane & 15, q = lane >> 4;
    const int wm = (w >> 1) * 64, wn = (w & 1) * 64;
    const int rb = w * 8 + (lane >> 3), kg = lane & 7;
    const int koff = (kg ^ (rb & 7)) * 8;
    const unsigned short* Ag = h1 + (size_t)(rowbase + rb) * HDIM + koff;
    const unsigned short* Bg = We2t + (size_t)eid * HDIM * HDIM
                             + (size_t)(blockIdx.x * 128 + rb) * HDIM + koff;
    unsigned short* Al = &As[rb * 64 + kg * 8];
    unsigned short* Bl = &Bs[rb * 64 + kg * 8];
    float4v acc[4][4];
#pragma unroll
    for (int i = 0; i < 4; ++i)
#pragma unroll
        for (int j = 0; j < 4; ++j) acc[i][j] = (float4v){0.f, 0.f, 0.f, 0.f};

    for (int kt = 0; kt < HDIM; kt += 64) {
        __syncthreads();
#pragma unroll
        for (int it = 0; it < 4; ++it) {
            gl_lds16(Ag + (size_t)it * 32 * HDIM + kt, Al + it * 32 * 64);
            gl_lds16(Bg + (size_t)it * 32 * HDIM + kt, Bl + it * 32 * 64);
        }
        __syncthreads();
#pragma unroll
        for (int kk = 0; kk < 2; ++kk) {
            short8 af[4], bf[4];
#pragma unroll
            for (int i = 0; i < 4; ++i)
                af[i] = *(const short8*)&As[(wm + 16 * i + ln) * 64 + (((kk * 4 + q) ^ (ln & 7)) * 8)];
#pragma unroll
            for (int j = 0; j < 4; ++j)
                bf[j] = *(const short8*)&Bs[(wn + 16 * j + ln) * 64 + (((kk * 4 + q) ^ (ln & 7)) * 8)];
#pragma unroll
            for (int i = 0; i < 4; ++i)
#pragma unroll
                for (int j = 0; j < 4; ++j)
                    acc[i][j] = __builtin_amdgcn_mfma_f32_16x16x32_bf16(af[i], bf[j], acc[i][j], 0, 0, 0);
        }
    }
    const int gn0 = blockIdx.x * 128 + wn;
#pragma unroll
    for (int i = 0; i < 4; ++i)
#pragma unroll
        for (int r = 0; r < 4; ++r) {
            int slot = rowbase + wm + 16 * i + q * 4 + r;
            int node = rowlist[slot];
            if (node >= 0) {
                float gt = gateval[slot];
#pragma unroll
                for (int j = 0; j < 4; ++j) {
                    int gn = gn0 + 16 * j + ln;
                    size_t o = (size_t)node * HDIM + gn;
                    float v = gt * (acc[i][j][r] + be2[eid * HDIM + gn]);
                    nf[o] = RMW ? f2b(b2f(nf[o]) + v) : f2b(v);
                }
            }
        }
}

// ---------- GNN fused layer: C = relu([h, agg] @ [Wself; Wnbr])  (K=1024 concat) ----------
template<int FINAL>
__global__ __launch_bounds__(256) void gemm_gnn(
    const unsigned short* __restrict__ A0, const unsigned short* __restrict__ A1,
    const unsigned short* __restrict__ Bt, unsigned short* __restrict__ Cb,
    float* __restrict__ Cf) {
    __shared__ unsigned short As[128 * 64];
    __shared__ unsigned short Bs[128 * 64];
    const int t = threadIdx.x, w = t >> 6, lane = t & 63;
    const int ln = lane & 15, q = lane >> 4;
    const int wm = (w >> 1) * 64, wn = (w & 1) * 64;
    const int rb = w * 8 + (lane >> 3), kg = lane & 7;
    const int koff = (kg ^ (rb & 7)) * 8;
    const unsigned short* Ag0 = A0 + (size_t)(blockIdx.y * 128 + rb) * HDIM + koff;
    const unsigned short* Ag1 = A1 + (size_t)(blockIdx.y * 128 + rb) * HDIM + koff;
    const unsigned short* Bg  = Bt + (size_t)(blockIdx.x * 128 + rb) * 1024 + koff;
    unsigned short* Al = &As[rb * 64 + kg * 8];
    unsigned short* Bl = &Bs[rb * 64 + kg * 8];
    float4v acc[4][4];
#pragma unroll
    for (int i = 0; i < 4; ++i)
#pragma unroll
        for (int j = 0; j < 4; ++j) acc[i][j] = (float4v){0.f, 0.f, 0.f, 0.f};

    for (int kt = 0; kt < 1024; kt += 64) {
        __syncthreads();
#pragma unroll
        for (int it = 0; it < 4; ++it) {
            const unsigned short* asrc = (kt < HDIM)
                ? (Ag0 + (size_t)it * 32 * HDIM + kt)
                : (Ag1 + (size_t)it * 32 * HDIM + (kt - HDIM));
            gl_lds16(asrc, Al + it * 32 * 64);
            gl_lds16(Bg + (size_t)it * 32 * 1024 + kt, Bl + it * 32 * 64);
        }
        __syncthreads();
#pragma unroll
        for (int kk = 0; kk < 2; ++kk) {
            short8 af[4], bf[4];
#pragma unroll
            for (int i = 0; i < 4; ++i)
                af[i] = *(const short8*)&As[(wm + 16 * i + ln) * 64 + (((kk * 4 + q) ^ (ln & 7)) * 8)];
#pragma unroll
            for (int j = 0; j < 4; ++j)
                bf[j] = *(const short8*)&Bs[(wn + 16 * j + ln) * 64 + (((kk * 4 + q) ^ (ln & 7)) * 8)];
#pragma unroll
            for (int i = 0; i < 4; ++i)
#pragma unroll
                for (int j = 0; j < 4; ++j)
                    acc[i][j] = __builtin_amdgcn_mfma_f32_16x16x32_bf16(af[i], bf[j], acc[i][j], 0, 0, 0);
        }
    }
    const int gm0 = blockIdx.y * 128 + wm;
    const int gn0 = blockIdx.x * 128 + wn;
#pragma unroll
    for (int i = 0; i < 4; ++i)
#pragma unroll
        for (int j = 0; j < 4; ++j) {
            int gn = gn0 + 16 * j + ln;
#pragma unroll
            for (int r = 0; r < 4; ++r) {
                int gm = gm0 + 16 * i + q * 4 + r;
                float v = fmaxf(acc[i][j][r], 0.f);
                if (FINAL) {
                    if (gm < NNODE) Cf[(size_t)gm * HDIM + gn] = v;
                } else {
                    Cb[(size_t)gm * HDIM + gn] = f2b(v);
                }
            }
        }
}

// ---------- CSR build ----------
__global__ void hist_kernel(const int* __restrict__ dst, int* __restrict__ deg) {
    int i = blockIdx.x * blockDim.x + threadIdx.x;
    if (i < NEDGE) atomicAdd(&deg[dst[i]], 1);
}
__global__ void scan_block(const int* __restrict__ in, int* __restrict__ incl,
                           int* __restrict__ bsum, int n) {
    __shared__ int s[256];
    int i = blockIdx.x * 256 + threadIdx.x;
    s[threadIdx.x] = (i < n) ? in[i] : 0;
    __syncthreads();
    for (int off = 1; off < 256; off <<= 1) {
        int t = (threadIdx.x >= (unsigned)off) ? s[threadIdx.x - off] : 0;
        __syncthreads();
        s[threadIdx.x] += t;
        __syncthreads();
    }
    if (i < n) incl[i] = s[threadIdx.x];
    if (bsum != nullptr && threadIdx.x == 255) bsum[blockIdx.x] = s[255];
}
__global__ void scan_fix(const int* __restrict__ incl, const int* __restrict__ deg,
                         const int* __restrict__ bscan, int* __restrict__ rowstart,
                         int* __restrict__ ecur) {
    int i = blockIdx.x * blockDim.x + threadIdx.x;
    if (i < NNODE) {
        int b = i >> 8;
        int add = (b > 0) ? bscan[b - 1] : 0;
        int st = incl[i] - deg[i] + add;
        rowstart[i] = st;
        ecur[i] = st;
    }
}
__global__ void fill_csr(const int* __restrict__ src, const int* __restrict__ dst,
                         int* __restrict__ ecur, int* __restrict__ srcs) {
    int e = blockIdx.x * blockDim.x + threadIdx.x;
    if (e < NEDGE) {
        int pos = atomicAdd(&ecur[dst[e]], 1);
        srcs[pos] = src[e];
    }
}

// ---------- segment-sum of bf16 rows -> bf16: agg[n] = sum_{s in nbrs(n)} h[s] ----------
__global__ __launch_bounds__(256) void msg_sum_b(
    const unsigned short* __restrict__ h, const int* __restrict__ rowstart,
    const int* __restrict__ deg, const int* __restrict__ srcs,
    unsigned short* __restrict__ agg) {
    __shared__ float sm[4][HDIM];
    int n = blockIdx.x;
    int wv = threadIdx.x >> 6, lane = threadIdx.x & 63;
    int st = rowstart[n], d = deg[n];
    float acc[8] = {0.f,0.f,0.f,0.f,0.f,0.f,0.f,0.f};
    for (int t = wv; t < d; t += 4) {
        int s = srcs[st + t];
        short8 v = *(const short8*)(h + (size_t)s * HDIM + lane * 8);
#pragma unroll
        for (int c = 0; c < 8; ++c) acc[c] += b2f((unsigned short)v[c]);
    }
#pragma unroll
    for (int c = 0; c < 8; ++c) sm[wv][lane * 8 + c] = acc[c];
    __syncthreads();
    if (threadIdx.x < 128) {
        int c0 = threadIdx.x * 4;
        ushort4v o;
#pragma unroll
        for (int c = 0; c < 4; ++c)
            o[c] = f2b(sm[0][c0 + c] + sm[1][c0 + c] + sm[2][c0 + c] + sm[3][c0 + c]);
        *(ushort4v*)(agg + (size_t)n * HDIM + c0) = o;
    }
}

extern "C" void kernel_launch(void* const* d_in, const int* in_sizes, int n_in,
                              void* d_out, int out_size, void* d_ws, size_t ws_size,
                              hipStream_t stream) {
    (void)in_sizes; (void)n_in; (void)out_size; (void)ws_size;
    const float* text       = (const float*)d_in[0];
    const float* tabular    = (const float*)d_in[1];
    const float* structured = (const float*)d_in[2];
    const int*   e_in       = (const int*)d_in[3];
    const float* Wg1  = (const float*)d_in[4];
    const float* bg1  = (const float*)d_in[5];
    const float* Wg2  = (const float*)d_in[6];
    const float* bg2  = (const float*)d_in[7];
    const float* We1  = (const float*)d_in[8];
    const float* be1  = (const float*)d_in[9];
    const float* We2  = (const float*)d_in[10];
    const float* be2  = (const float*)d_in[11];
    const float* Wself = (const float*)d_in[12];
    const float* Wnbr  = (const float*)d_in[13];
    const int* src = e_in;
    const int* dst = e_in + NEDGE;
    float* dout = (float*)d_out;

    // ---- workspace carve-up (regions overlap across phases; ~220 MB total) ----
    char* w = (char*)d_ws;
    auto alloc = [&](size_t bytes) { char* p = w; w += (bytes + 511) & ~(size_t)511; return p; };
    const size_t SZ_H = (size_t)M_PAD * HDIM * 2;            // 51.25 MB
    unsigned short* We1t  = (unsigned short*)alloc((size_t)NEXP * HDIM * EDIM * 2);
    unsigned short* We2t  = (unsigned short*)alloc((size_t)NEXP * HDIM * HDIM * 2);
    unsigned short* Wcat0 = (unsigned short*)alloc((size_t)HDIM * 1024 * 2);
    unsigned short* Wcat1 = (unsigned short*)alloc((size_t)HDIM * 1024 * 2);
    unsigned short* Wg1h  = (unsigned short*)alloc((size_t)GHID * 768 * 2);
    unsigned short* Wg1l  = (unsigned short*)alloc((size_t)GHID * 768 * 2);
    float* gates    = (float*)alloc((size_t)NNODE * 2 * 4);
    int*   esel     = (int*)alloc((size_t)NNODE * 2 * 4);
    int*   slotcnt  = (int*)alloc(16 * 4);
    int*   scursor  = (int*)alloc(16 * 4);
    int*   header   = (int*)alloc(16 * 4);
    int2*  meta_all = (int2*)alloc((size_t)MAXT_ALL * 8);
    int2*  meta_r0  = (int2*)alloc((size_t)MAXT_R * 8);
    int2*  meta_r1  = (int2*)alloc((size_t)MAXT_R * 8);
    int*   rowlist  = (int*)alloc((size_t)SLOTCAP * 4);
    float* gateval  = (float*)alloc((size_t)SLOTCAP * 4);
    int*   deg      = (int*)alloc((size_t)NNODE * 4);
    int*   incl     = (int*)alloc((size_t)NNODE * 4);
    int*   bsum     = (int*)alloc(1024 * 4);
    int*   bscan    = (int*)alloc(1024 * 4);
    int*   rowstart = (int*)alloc((size_t)NNODE * 4);
    int*   ecur     = (int*)alloc((size_t)NNODE * 4);
    int*   srcs     = (int*)alloc((size_t)NEDGE * 4);
    unsigned short* nfb = (unsigned short*)alloc(SZ_H);
    // region A: gbuf (gate hidden, fp32) dead after gating; aggb alive only in GNN
    char* regA = alloc((size_t)M_PAD * GHID * 4 > SZ_H ? (size_t)M_PAD * GHID * 4 : SZ_H);
    float*          gbuf = (float*)regA;
    unsigned short* aggb = (unsigned short*)regA;
    // region B: h1c (compacted expert hidden) dead after moe2; hb alive only in GNN
    char* regB = alloc((size_t)SLOTCAP * HDIM * 2);
    unsigned short* h1c = (unsigned short*)regB;
    unsigned short* hb  = (unsigned short*)regB;

    // ---- weight prep ----
    wtrans  <<<512, 256, 0, stream>>>(We1, We1t, NEXP, EDIM, HDIM);
    wtrans  <<<512, 256, 0, stream>>>(We2, We2t, NEXP, HDIM, HDIM);
    wtrans_k<<<512, 256, 0, stream>>>(Wself,               Wcat0, HDIM, HDIM, 1024, 0);
    wtrans_k<<<512, 256, 0, stream>>>(Wnbr,                Wcat0, HDIM, HDIM, 1024, 512);
    wtrans_k<<<512, 256, 0, stream>>>(Wself + HDIM * HDIM, Wcat1, HDIM, HDIM, 1024, 0);
    wtrans_k<<<512, 256, 0, stream>>>(Wnbr  + HDIM * HDIM, Wcat1, HDIM, HDIM, 1024, 512);
    wtrans2 <<<512, 256, 0, stream>>>(Wg1, Wg1h, Wg1l, 3 * EDIM, GHID);

    hipMemsetAsync(slotcnt, 0, 16 * 4, stream);
    hipMemsetAsync(rowlist, 0xFF, (size_t)SLOTCAP * 4, stream);
    hipMemsetAsync(deg, 0, (size_t)NNODE * 4, stream);

    // ---- gate (bf16x3 split, fp32 fidelity) + routing ----
    gate128<<<dim3(1, M_PAD / 128), 256, 0, stream>>>(text, tabular, structured,
                                                      Wg1h, Wg1l, bg1, gbuf);
    gating<<<NNODE / 4, 256, 0, stream>>>(gbuf, Wg2, bg2, gates, esel);

    // ---- compaction plan ----
    slot_count<<<(NNODE + 255) / 256, 256, 0, stream>>>(esel, slotcnt);
    seg_plan<<<1, 64, 0, stream>>>(slotcnt, scursor, header, meta_all, meta_r0, meta_r1);
    slot_fill<<<(NNODE + 255) / 256, 256, 0, stream>>>(esel, gates, scursor, rowlist, gateval);

    // ---- experts on routed rows only ----
    gemm_moe1<<<dim3(HDIM / 128, MAXT_ALL), 256, 0, stream>>>(
        tabular, structured, text, We1t, be1, header, meta_all, rowlist, h1c);
    gemm_moe2<0><<<dim3(HDIM / 128, MAXT_R), 256, 0, stream>>>(
        h1c, We2t, be2, header, meta_r0, rowlist, gateval, nfb);
    gemm_moe2<1><<<dim3(HDIM / 128, MAXT_R), 256, 0, stream>>>(
        h1c, We2t, be2, header, meta_r1, rowlist, gateval, nfb);

    // ---- CSR of edges grouped by dst ----
    const int NB = (NNODE + 255) / 256;
    hist_kernel<<<(NEDGE + 255) / 256, 256, 0, stream>>>(dst, deg);
    scan_block<<<NB, 256, 0, stream>>>(deg, incl, bsum, NNODE);
    scan_block<<<1, 256, 0, stream>>>(bsum, bscan, nullptr, NB);
    scan_fix<<<NB, 256, 0, stream>>>(incl, deg, bscan, rowstart, ecur);
    fill_csr<<<(NEDGE + 255) / 256, 256, 0, stream>>>(src, dst, ecur, srcs);

    // ---- GNN layer 0: agg = segsum(nf); h = relu([nf,agg] @ Wcat0) ----
    msg_sum_b<<<NNODE, 256, 0, stream>>>(nfb, rowstart, deg, srcs, aggb);
    gemm_gnn<0><<<dim3(HDIM / 128, M_PAD / 128), 256, 0, stream>>>(nfb, aggb, Wcat0, hb, nullptr);

    // ---- GNN layer 1: agg = segsum(h); out = relu([h,agg] @ Wcat1) ----
    msg_sum_b<<<NNODE, 256, 0, stream>>>(hb, rowstart, deg, srcs, aggb);
    gemm_gnn<1><<<dim3(HDIM / 128, M_PAD / 128), 256, 0, stream>>>(hb, aggb, Wcat1, nullptr, dout);
}